// Round 16
// baseline (223.558 us; speedup 1.0000x reference)
//
#include <hip/hip_runtime.h>

// VectorQuantizer: inputs [8,4096,64] f32, weight [8192,64] f32.
// Outputs concat: quantized_st [2097152] f32, loss [1] f32, indices [32768] f32.
//
// R20 = R19 (211.4us, passing) with tail Phase-B RB 4->8: one 2 MB wT sweep
// now covers up to 8 flagged rows (nf~Poisson(4)/block: P[nf>8]~2%), removing
// the ~37% second sweeps (E[ceil(nf/4)]=1.37 -> ~1.0 sweeps/block; ~1.4 GB ->
// ~1.0 GB L2 + no second-sweep FMA pass). Register budget explicitly counted
// (R13/R16 spill lessons): s[8][4]=32 + 4 in-flight w4=16 + bkey[8](u64)=16
// + addressing ~= 100 VGPR < 128 cliff; i-unroll stays 4, c-loop stays serial.
// argmin: R6/R19 config (KSPLIT=4, 4-tile group, 32 KB dbuf LDS; 106us,
// MfmaUtil 43%). prep (wsq/wsqb/packedW/wT) byte-identical to R19.

typedef short bf16x8 __attribute__((ext_vector_type(8)));
typedef float f32x4  __attribute__((ext_vector_type(4)));

#define N_ROWS 32768
#define DIM 64
#define K_CODES 8192
#define KSPLIT 4
#define KCHUNK 2048
#define OUT_Q 0
#define OUT_LOSS 2097152
#define OUT_IDX 2097153
#define MARGIN 4e-4f
#define KEYMASK 0xFFFFFF80u
#define TROWS 64     // rows per tail block
#define RB 8         // flagged rows per batched codebook sweep

// ---- helpers ----
__device__ __forceinline__ unsigned f2u_ord(float f) {
    unsigned u = __float_as_uint(f);
    return (u & 0x80000000u) ? ~u : (u | 0x80000000u);
}
__device__ __forceinline__ unsigned short bf16_rne(float f) {
    unsigned u = __float_as_uint(f);
    u += 0x7fffu + ((u >> 16) & 1u);
    return (unsigned short)(u >> 16);
}
__device__ __forceinline__ float bf16_to_f(unsigned short h) {
    return __uint_as_float(((unsigned)h) << 16);
}

// numpy pairwise_sum over 64 squared elements (exact np emulation)
__device__ __forceinline__ float np_pairwise_sq64(const float* v) {
    float r[8];
#pragma unroll
    for (int j = 0; j < 8; j++) r[j] = __fmul_rn(v[j], v[j]);
#pragma unroll
    for (int i = 8; i < 64; i += 8) {
#pragma unroll
        for (int j = 0; j < 8; j++)
            r[j] = __fadd_rn(r[j], __fmul_rn(v[i + j], v[i + j]));
    }
    return __fadd_rn(__fadd_rn(__fadd_rn(r[0], r[1]), __fadd_rn(r[2], r[3])),
                     __fadd_rn(__fadd_rn(r[4], r[5]), __fadd_rn(r[6], r[7])));
}

// ------------- kernel 0: prep (wsq + wsqb + packedW + wT + loss zero) --------
// grid 128 x 256. Block covers codes [bx*64, bx*64+64).
__global__ __launch_bounds__(256) void vq_prep(const float* __restrict__ weight,
                                               float* __restrict__ wsq,
                                               float* __restrict__ wsqb,
                                               int4* __restrict__ packedW,
                                               float* __restrict__ wT,
                                               float* __restrict__ loss_out) {
    __shared__ float lt[64 * 65];   // 16.6 KB, 65-float padded rows
    int tid = threadIdx.x;
    if (blockIdx.x == 0 && tid == 0) *loss_out = 0.f;

    // ---- stage 64 codes into LDS (coalesced float4 reads) ----
#pragma unroll
    for (int k = 0; k < 4; ++k) {
        int id = tid + k * 256;          // 1024 float4 chunks
        int row = id >> 4, ch = id & 15;
        float4 v = ((const float4*)(weight + (size_t)(blockIdx.x * 64 + row) * DIM))[ch];
        lt[row * 65 + ch * 4 + 0] = v.x;
        lt[row * 65 + ch * 4 + 1] = v.y;
        lt[row * 65 + ch * 4 + 2] = v.z;
        lt[row * 65 + ch * 4 + 3] = v.w;
    }
    __syncthreads();
    // ---- transposed write: wT[i*K + bx*64 + c] (coalesced 256B stores) ----
#pragma unroll
    for (int k = 0; k < 16; ++k) {
        int id = tid + k * 256;          // 4096 elements
        int i = id >> 6, c = id & 63;
        wT[(size_t)i * K_CODES + blockIdx.x * 64 + c] = lt[c * 65 + i];
    }

    if (tid < 64) {
        int k = blockIdx.x * 64 + tid;
        float w[64];
        const float4* wp = (const float4*)(weight + (size_t)k * DIM);
#pragma unroll
        for (int i = 0; i < 16; i++) {
            float4 t = wp[i];
            w[4 * i] = t.x; w[4 * i + 1] = t.y; w[4 * i + 2] = t.z; w[4 * i + 3] = t.w;
        }
        float s = np_pairwise_sq64(w);
        wsq[k] = s;
        wsqb[k] = s + 8.0f;   // BIAS folded for the MFMA accumulator init
    }

    int wave = tid >> 6;
    int lane = tid & 63;
    int tile = blockIdx.x * 4 + wave;     // 0..511
    int code = tile * 16 + (lane & 15);
    int kq = (lane >> 4) * 8;
    const float* wr = weight + (size_t)code * DIM;

    union { bf16x8 v; int4 q; } hi0, hi1, lo0, lo1;
#pragma unroll
    for (int j = 0; j < 8; j++) {
        float a = -2.0f * wr[kq + j];
        unsigned short ha = bf16_rne(a);
        hi0.v[j] = (short)ha;
        lo0.v[j] = (short)bf16_rne(a - bf16_to_f(ha));
        float b = -2.0f * wr[32 + kq + j];
        unsigned short hb = bf16_rne(b);
        hi1.v[j] = (short)hb;
        lo1.v[j] = (short)bf16_rne(b - bf16_to_f(hb));
    }
    size_t base = (size_t)tile * 4 * 64;
    packedW[base + 0 * 64 + lane] = hi0.q;
    packedW[base + 1 * 64 + lane] = hi1.q;
    packedW[base + 2 * 64 + lane] = lo0.q;
    packedW[base + 3 * 64 + lane] = lo1.q;
}

// ---------------- kernel 1: MFMA argmin top-2 over a 2048-code chunk ----------
// grid (256, KSPLIT=4) x 256. Block: 128 rows; wave: 32 rows (2 row-tiles).
// Group = 4 code-tiles (16 KB); double-buffered -> 32 KB LDS (R6/R19 config).
__global__ __launch_bounds__(256) void vq_argmin_mfma(const float* __restrict__ inp,
                                                      const int4* __restrict__ packedW,
                                                      const float* __restrict__ wsqb,
                                                      unsigned long long* __restrict__ bestk,
                                                      unsigned* __restrict__ secd) {
    __shared__ int4 sB[2048];   // 32 KB: two 16 KB buffers (4 code-tiles each)
    int wave = threadIdx.x >> 6;
    int lane = threadIdx.x & 63;
    int rbase = blockIdx.x * 128 + wave * 32;
    int kbase = blockIdx.y * KCHUNK;

    int kq = (lane >> 4) * 8;
    bf16x8 ah[2][2], al[2][2];   // [row-tile][k-chunk]
#pragma unroll
    for (int rt = 0; rt < 2; rt++) {
        const float* xp = inp + (size_t)(rbase + rt * 16 + (lane & 15)) * DIM;
#pragma unroll
        for (int kc = 0; kc < 2; kc++) {
            const float* xq = xp + kc * 32 + kq;
#pragma unroll
            for (int j = 0; j < 8; j++) {
                float a = xq[j];
                unsigned short h = bf16_rne(a);
                ah[rt][kc][j] = (short)h;
                al[rt][kc][j] = (short)bf16_rne(a - bf16_to_f(h));
            }
        }
    }

    unsigned best[8], sec[8];
#pragma unroll
    for (int s = 0; s < 8; s++) { best[s] = 0xFFFFFFFFu; sec[s] = 0xFFFFFFFFu; }

    // stage one 16 KB group (4 tiles, wave w stages tile w) into buffer `buf`
#define STAGE(buf, g) do {                                                        \
        const char* _src = (const char*)packedW +                                 \
            ((size_t)(kbase >> 4) + (size_t)(g) * 4 + wave) * 4096;               \
        char* _dst = (char*)sB + (buf) * 16384 + wave * 4096;                     \
        _Pragma("unroll")                                                         \
        for (int _i = 0; _i < 4; _i++)                                            \
            __builtin_amdgcn_global_load_lds(                                     \
                (const __attribute__((address_space(1))) unsigned int*)(_src + _i * 1024 + lane * 16), \
                (__attribute__((address_space(3))) unsigned int*)(_dst + _i * 1024), \
                16, 0, 0);                                                        \
    } while (0)

    STAGE(0, 0);
    __syncthreads();   // drains vmcnt(0): buf0 ready

    for (int g = 0; g < 32; g++) {
        int buf = g & 1;
        if (g + 1 < 32) STAGE(buf ^ 1, g + 1);   // issue next-group loads FIRST
        int lane_code = kbase + g * 64 + (lane & 15);
#pragma unroll
        for (int t = 0; t < 4; t++) {
            const int4* bp = sB + buf * 1024 + t * 256;
            union { int4 q; bf16x8 v; } bh0, bh1, bl0, bl1;
            bh0.q = bp[0 * 64 + lane];
            bh1.q = bp[1 * 64 + lane];
            bl0.q = bp[2 * 64 + lane];
            bl1.q = bp[3 * 64 + lane];
            float wq = wsqb[lane_code + t * 16];
            unsigned tid7 = (unsigned)(g * 4 + t);   // 0..127 tile id in chunk
#pragma unroll
            for (int rt = 0; rt < 2; rt++) {
                f32x4 acc = {wq, wq, wq, wq};   // c = wsq + 8 - 2*dot, directly
                acc = __builtin_amdgcn_mfma_f32_16x16x32_bf16(ah[rt][0], bh0.v, acc, 0, 0, 0);
                acc = __builtin_amdgcn_mfma_f32_16x16x32_bf16(ah[rt][1], bh1.v, acc, 0, 0, 0);
                acc = __builtin_amdgcn_mfma_f32_16x16x32_bf16(al[rt][0], bh0.v, acc, 0, 0, 0);
                acc = __builtin_amdgcn_mfma_f32_16x16x32_bf16(al[rt][1], bh1.v, acc, 0, 0, 0);
                acc = __builtin_amdgcn_mfma_f32_16x16x32_bf16(ah[rt][0], bl0.v, acc, 0, 0, 0);
                acc = __builtin_amdgcn_mfma_f32_16x16x32_bf16(ah[rt][1], bl1.v, acc, 0, 0, 0);
#pragma unroll
                for (int r = 0; r < 4; r++) {
                    unsigned key = (__float_as_uint(acc[r]) & KEYMASK) | tid7;
                    int s = rt * 4 + r;
                    unsigned mx = best[s] > key ? best[s] : key;
                    sec[s] = sec[s] < mx ? sec[s] : mx;
                    best[s] = best[s] < key ? best[s] : key;
                }
            }
        }
        __syncthreads();   // one barrier per group; also drains next-group loads
    }
#undef STAGE

    unsigned col[8];
#pragma unroll
    for (int s = 0; s < 8; s++) col[s] = lane & 15;
#pragma unroll
    for (int m = 1; m < 16; m <<= 1) {
#pragma unroll
        for (int s = 0; s < 8; s++) {
            unsigned ok = (unsigned)__shfl_xor((int)best[s], m, 64);
            unsigned os = (unsigned)__shfl_xor((int)sec[s], m, 64);
            unsigned oc = (unsigned)__shfl_xor((int)col[s], m, 64);
            unsigned mx = best[s] > ok ? best[s] : ok;
            unsigned mn2 = sec[s] < os ? sec[s] : os;
            sec[s] = mn2 < mx ? mn2 : mx;
            bool take = ok < best[s];
            best[s] = take ? ok : best[s];
            col[s] = take ? oc : col[s];
        }
    }
    if ((lane & 15) == 0) {
        int g4 = lane >> 4;
#pragma unroll
        for (int rt = 0; rt < 2; rt++)
#pragma unroll
            for (int r = 0; r < 4; r++) {
                int row = rbase + rt * 16 + g4 * 4 + r;
                int s = rt * 4 + r;
                int code = kbase + (int)(best[s] & 127u) * 16 + (int)col[s];
                bestk[(size_t)blockIdx.y * N_ROWS + row] =
                    ((unsigned long long)best[s] << 32) | (unsigned)code;
                secd[(size_t)blockIdx.y * N_ROWS + row] = sec[s];
            }
    }
}

// ---------------- kernel 2: fused merge + COALESCED recheck + final ----------
// grid 512 x 256. Block owns rows [bx*64, bx*64+64): merge (idx in LDS) ->
// flagged rows rescanned in batches of RB=8 with ONE coalesced codebook sweep
// per batch via wT -> gather/STE/loss. No cross-block data flow.
__global__ __launch_bounds__(256) void vq_tail(const float* __restrict__ inp,
                                               const float* __restrict__ weight,
                                               const float* __restrict__ wsq,
                                               const float* __restrict__ wT,
                                               const unsigned long long* __restrict__ bestk,
                                               const unsigned* __restrict__ secd,
                                               float* __restrict__ out) {
    __shared__ int idx_lds[TROWS];
    __shared__ int rowlist[TROWS];
    __shared__ int nf_s;
    __shared__ float xs[RB][DIM];
    __shared__ float x2s[RB];
    __shared__ unsigned long long wk[4];
    __shared__ float red[4];

    int tid = threadIdx.x;
    int lane = tid & 63;
    int wave = tid >> 6;
    int rbase = blockIdx.x * TROWS;

    if (tid == 0) nf_s = 0;
    __syncthreads();

    // ---- Phase A: merge KSPLIT chunks (proven merge math) ----
    if (tid < TROWS) {
        int row = rbase + tid;
        unsigned long long ks[KSPLIT];
        unsigned ss[KSPLIT];
#pragma unroll
        for (int c = 0; c < KSPLIT; c++) {
            ks[c] = bestk[(size_t)c * N_ROWS + row];
            ss[c] = secd[(size_t)c * N_ROWS + row];
        }
        unsigned long long k1 = ks[0];
#pragma unroll
        for (int c = 1; c < KSPLIT; c++) k1 = (ks[c] < k1) ? ks[c] : k1;
        unsigned d2 = 0xFFFFFFFFu;
#pragma unroll
        for (int c = 0; c < KSPLIT; c++) {
            if (ks[c] != k1) {
                unsigned b = (unsigned)(ks[c] >> 32);
                d2 = b < d2 ? b : d2;
            }
            d2 = ss[c] < d2 ? ss[c] : d2;
        }
        idx_lds[tid] = (int)(k1 & 0xffffffffull);
        float f1 = __uint_as_float(((unsigned)(k1 >> 32)) & KEYMASK);
        float f2 = __uint_as_float(d2 & KEYMASK);
        if (f2 - f1 < MARGIN) {
            int slot = atomicAdd(&nf_s, 1);
            rowlist[slot] = tid;       // local row id
        }
    }
    __syncthreads();
    int nf = nf_s;

    // ---- Phase B: batched rescan via transposed codebook (coalesced) ----
    for (int f0 = 0; f0 < nf; f0 += RB) {
        int nr = nf - f0; if (nr > RB) nr = RB;

        for (int e = tid; e < nr * DIM; e += 256) {
            int r = e >> 6;
            xs[r][e & 63] = inp[(size_t)(rbase + rowlist[f0 + r]) * DIM + (e & 63)];
        }
        __syncthreads();
        if (tid < nr) x2s[tid] = np_pairwise_sq64(xs[tid]);
        __syncthreads();
        // rows beyond nr: stale/uninit LDS -> garbage distances; their bkey is
        // never consumed (reduce loop breaks at nr). NaN keys map to large
        // ordered values (benign).

        unsigned long long bkey[RB];
#pragma unroll
        for (int r = 0; r < RB; r++) bkey[r] = 0xFFFFFFFFFFFFFFFFull;

#pragma unroll 1   // serial over code-quads (register budget: R13/R16 lesson)
        for (int it = 0; it < K_CODES / 1024; ++it) {   // 8 iters, 4 codes/thread
            int code0 = it * 1024 + tid * 4;
            float s[RB][4];
#pragma unroll
            for (int r = 0; r < RB; r++)
#pragma unroll
                for (int q = 0; q < 4; q++) s[r][q] = 0.f;
#pragma unroll 4   // 4 float4 of wT in flight (16 VGPR)
            for (int i = 0; i < DIM; ++i) {
                float4 w4 = *(const float4*)(wT + (size_t)i * K_CODES + code0);
#pragma unroll
                for (int r = 0; r < RB; r++) {
                    float xv = xs[r][i];
                    s[r][0] = __builtin_fmaf(xv, w4.x, s[r][0]);
                    s[r][1] = __builtin_fmaf(xv, w4.y, s[r][1]);
                    s[r][2] = __builtin_fmaf(xv, w4.z, s[r][2]);
                    s[r][3] = __builtin_fmaf(xv, w4.w, s[r][3]);
                }
            }
            float4 wsq4 = *(const float4*)(wsq + code0);
#pragma unroll
            for (int r = 0; r < RB; r++) {
                float w0 = wsq4.x, w1 = wsq4.y, w2 = wsq4.z, w3 = wsq4.w;
                float d0 = __fsub_rn(__fadd_rn(x2s[r], w0), __fmul_rn(2.0f, s[r][0]));
                float d1 = __fsub_rn(__fadd_rn(x2s[r], w1), __fmul_rn(2.0f, s[r][1]));
                float d2 = __fsub_rn(__fadd_rn(x2s[r], w2), __fmul_rn(2.0f, s[r][2]));
                float d3 = __fsub_rn(__fadd_rn(x2s[r], w3), __fmul_rn(2.0f, s[r][3]));
                unsigned long long k0 = ((unsigned long long)f2u_ord(d0) << 32) | (unsigned)(code0 + 0);
                unsigned long long k1 = ((unsigned long long)f2u_ord(d1) << 32) | (unsigned)(code0 + 1);
                unsigned long long k2 = ((unsigned long long)f2u_ord(d2) << 32) | (unsigned)(code0 + 2);
                unsigned long long k3 = ((unsigned long long)f2u_ord(d3) << 32) | (unsigned)(code0 + 3);
                unsigned long long m01 = k0 < k1 ? k0 : k1;
                unsigned long long m23 = k2 < k3 ? k2 : k3;
                unsigned long long m = m01 < m23 ? m01 : m23;
                bkey[r] = m < bkey[r] ? m : bkey[r];
            }
        }

        // per-row reduce: wave shuffle-min -> LDS -> thread 0 writes idx_lds
#pragma unroll 1
        for (int r = 0; r < RB; r++) {
            if (r >= nr) break;   // nr is block-uniform: no divergence hazard
            unsigned long long k = bkey[r];
#pragma unroll
            for (int m = 1; m < 64; m <<= 1) {
                unsigned hi = (unsigned)(k >> 32), lo = (unsigned)k;
                unsigned ohi = (unsigned)__shfl_xor((int)hi, m, 64);
                unsigned olo = (unsigned)__shfl_xor((int)lo, m, 64);
                unsigned long long o = ((unsigned long long)ohi << 32) | olo;
                k = o < k ? o : k;
            }
            if (lane == 0) wk[wave] = k;
            __syncthreads();
            if (tid == 0) {
                unsigned long long kk = wk[0];
#pragma unroll
                for (int w = 1; w < 4; w++) kk = wk[w] < kk ? wk[w] : kk;
                idx_lds[rowlist[f0 + r]] = (int)(kk & 0xffffffffull);
            }
            __syncthreads();
        }
    }

    // ---- Phase C: gather + STE + loss + index (from LDS idx) ----
    float lp = 0.f;
#pragma unroll
    for (int i = 0; i < (TROWS * 16) / 256; ++i) {   // 4 float4 per thread
        int e = i * 256 + tid;
        int lr = e >> 4;
        int sub = e & 15;
        int row = rbase + lr;
        int idx = idx_lds[lr];

        float4 x = ((const float4*)inp)[(size_t)row * 16 + sub];
        float4 w = ((const float4*)weight)[(size_t)idx * 16 + sub];

        float4 q;
        q.x = x.x + (w.x - x.x);
        q.y = x.y + (w.y - x.y);
        q.z = x.z + (w.z - x.z);
        q.w = x.w + (w.w - x.w);
        ((float4*)(out + OUT_Q))[(size_t)row * 16 + sub] = q;

        if (sub == 0) out[OUT_IDX + row] = (float)idx;

        float dx = w.x - x.x, dy = w.y - x.y, dz = w.z - x.z, dw = w.w - x.w;
        lp += dx * dx + dy * dy + dz * dz + dw * dw;
    }
#pragma unroll
    for (int o = 32; o > 0; o >>= 1) lp += __shfl_down(lp, o, 64);
    if (lane == 0) red[wave] = lp;
    __syncthreads();
    if (tid == 0) {
        float bs = red[0] + red[1] + red[2] + red[3];
        atomicAdd(out + OUT_LOSS, bs * (0.25f / 2097152.f));
    }
}

extern "C" void kernel_launch(void* const* d_in, const int* in_sizes, int n_in,
                              void* d_out, int out_size, void* d_ws, size_t ws_size,
                              hipStream_t stream) {
    const float* inp = (const float*)d_in[0];
    const float* weight = (const float*)d_in[1];
    float* out = (float*)d_out;

    char* p = (char*)d_ws;
    unsigned long long* bestk = (unsigned long long*)p; p += (size_t)KSPLIT * N_ROWS * 8; // 1 MB
    unsigned* secd  = (unsigned*)p;            p += (size_t)KSPLIT * N_ROWS * 4;          // 512 KB
    float* wsq      = (float*)p;               p += (size_t)K_CODES * 4;                  // 32 KB
    float* wsqb     = (float*)p;               p += (size_t)K_CODES * 4;                  // 32 KB
    int4* packedW   = (int4*)p;                p += (size_t)512 * 4 * 64 * 16;            // 2 MB
    float* wT       = (float*)p;               p += (size_t)DIM * K_CODES * 4;            // 2 MB

    vq_prep<<<128, 256, 0, stream>>>(weight, wsq, wsqb, packedW, wT, out + OUT_LOSS);
    vq_argmin_mfma<<<dim3(N_ROWS / 128, KSPLIT), 256, 0, stream>>>(
        inp, packedW, wsqb, bestk, secd);
    vq_tail<<<N_ROWS / TROWS, 256, 0, stream>>>(inp, weight, wsq, wT, bestk, secd, out);
}

// Round 17
// 210.095 us; speedup vs baseline: 1.0641x; 1.0641x over previous
//
#include <hip/hip_runtime.h>

// VectorQuantizer: inputs [8,4096,64] f32, weight [8192,64] f32.
// Outputs concat: quantized_st [2097152] f32, loss [1] f32, indices [32768] f32.
//
// R21 = R19 verbatim (session best: 211.4us, passing; baseline 273.4us).
// R20's RB=8 tail regressed (223.6us): the sweep computes all RB rows
// regardless of nf, so 62% of blocks (nf<=4) paid double FMA; RB=4 is the
// measured optimum. Final structure:
//   prep:   wsq/wsqb + bf16-split packedW(-2w) + wT transpose (LDS-staged)
//   argmin: MFMA top-2, KSPLIT=4 x 2048-code chunks, 4-tile 16KB groups
//           double-buffered (32KB LDS), global_load_lds staging, key-space
//           tracking (4 VALU/elem), wsq+8 bias folded into acc init
//           [106us, MfmaUtil 43%, VALUBusy 60%, bank conflicts 0]
//   tail:   fused merge + batched np-exact recheck (RB=4 rows per coalesced
//           wT sweep) + gather/STE/loss; no cross-block data flow
// Exactness: bf16 3-term split error ~5e-5 + 128-ULP key quantization, both
// < MARGIN=4e-4 -> every ambiguous row rescanned np-exactly (ascending
// strict-<, u64 ordered key == np argmin tie-break).

typedef short bf16x8 __attribute__((ext_vector_type(8)));
typedef float f32x4  __attribute__((ext_vector_type(4)));

#define N_ROWS 32768
#define DIM 64
#define K_CODES 8192
#define KSPLIT 4
#define KCHUNK 2048
#define OUT_Q 0
#define OUT_LOSS 2097152
#define OUT_IDX 2097153
#define MARGIN 4e-4f
#define KEYMASK 0xFFFFFF80u
#define TROWS 64     // rows per tail block
#define RB 4         // flagged rows per batched codebook sweep

// ---- helpers ----
__device__ __forceinline__ unsigned f2u_ord(float f) {
    unsigned u = __float_as_uint(f);
    return (u & 0x80000000u) ? ~u : (u | 0x80000000u);
}
__device__ __forceinline__ unsigned short bf16_rne(float f) {
    unsigned u = __float_as_uint(f);
    u += 0x7fffu + ((u >> 16) & 1u);
    return (unsigned short)(u >> 16);
}
__device__ __forceinline__ float bf16_to_f(unsigned short h) {
    return __uint_as_float(((unsigned)h) << 16);
}

// numpy pairwise_sum over 64 squared elements (exact np emulation)
__device__ __forceinline__ float np_pairwise_sq64(const float* v) {
    float r[8];
#pragma unroll
    for (int j = 0; j < 8; j++) r[j] = __fmul_rn(v[j], v[j]);
#pragma unroll
    for (int i = 8; i < 64; i += 8) {
#pragma unroll
        for (int j = 0; j < 8; j++)
            r[j] = __fadd_rn(r[j], __fmul_rn(v[i + j], v[i + j]));
    }
    return __fadd_rn(__fadd_rn(__fadd_rn(r[0], r[1]), __fadd_rn(r[2], r[3])),
                     __fadd_rn(__fadd_rn(r[4], r[5]), __fadd_rn(r[6], r[7])));
}

// ------------- kernel 0: prep (wsq + wsqb + packedW + wT + loss zero) --------
// grid 128 x 256. Block covers codes [bx*64, bx*64+64).
__global__ __launch_bounds__(256) void vq_prep(const float* __restrict__ weight,
                                               float* __restrict__ wsq,
                                               float* __restrict__ wsqb,
                                               int4* __restrict__ packedW,
                                               float* __restrict__ wT,
                                               float* __restrict__ loss_out) {
    __shared__ float lt[64 * 65];   // 16.6 KB, 65-float padded rows
    int tid = threadIdx.x;
    if (blockIdx.x == 0 && tid == 0) *loss_out = 0.f;

    // ---- stage 64 codes into LDS (coalesced float4 reads) ----
#pragma unroll
    for (int k = 0; k < 4; ++k) {
        int id = tid + k * 256;          // 1024 float4 chunks
        int row = id >> 4, ch = id & 15;
        float4 v = ((const float4*)(weight + (size_t)(blockIdx.x * 64 + row) * DIM))[ch];
        lt[row * 65 + ch * 4 + 0] = v.x;
        lt[row * 65 + ch * 4 + 1] = v.y;
        lt[row * 65 + ch * 4 + 2] = v.z;
        lt[row * 65 + ch * 4 + 3] = v.w;
    }
    __syncthreads();
    // ---- transposed write: wT[i*K + bx*64 + c] (coalesced 256B stores) ----
#pragma unroll
    for (int k = 0; k < 16; ++k) {
        int id = tid + k * 256;          // 4096 elements
        int i = id >> 6, c = id & 63;
        wT[(size_t)i * K_CODES + blockIdx.x * 64 + c] = lt[c * 65 + i];
    }

    if (tid < 64) {
        int k = blockIdx.x * 64 + tid;
        float w[64];
        const float4* wp = (const float4*)(weight + (size_t)k * DIM);
#pragma unroll
        for (int i = 0; i < 16; i++) {
            float4 t = wp[i];
            w[4 * i] = t.x; w[4 * i + 1] = t.y; w[4 * i + 2] = t.z; w[4 * i + 3] = t.w;
        }
        float s = np_pairwise_sq64(w);
        wsq[k] = s;
        wsqb[k] = s + 8.0f;   // BIAS folded for the MFMA accumulator init
    }

    int wave = tid >> 6;
    int lane = tid & 63;
    int tile = blockIdx.x * 4 + wave;     // 0..511
    int code = tile * 16 + (lane & 15);
    int kq = (lane >> 4) * 8;
    const float* wr = weight + (size_t)code * DIM;

    union { bf16x8 v; int4 q; } hi0, hi1, lo0, lo1;
#pragma unroll
    for (int j = 0; j < 8; j++) {
        float a = -2.0f * wr[kq + j];
        unsigned short ha = bf16_rne(a);
        hi0.v[j] = (short)ha;
        lo0.v[j] = (short)bf16_rne(a - bf16_to_f(ha));
        float b = -2.0f * wr[32 + kq + j];
        unsigned short hb = bf16_rne(b);
        hi1.v[j] = (short)hb;
        lo1.v[j] = (short)bf16_rne(b - bf16_to_f(hb));
    }
    size_t base = (size_t)tile * 4 * 64;
    packedW[base + 0 * 64 + lane] = hi0.q;
    packedW[base + 1 * 64 + lane] = hi1.q;
    packedW[base + 2 * 64 + lane] = lo0.q;
    packedW[base + 3 * 64 + lane] = lo1.q;
}

// ---------------- kernel 1: MFMA argmin top-2 over a 2048-code chunk ----------
// grid (256, KSPLIT=4) x 256. Block: 128 rows; wave: 32 rows (2 row-tiles).
// Group = 4 code-tiles (16 KB); double-buffered -> 32 KB LDS.
__global__ __launch_bounds__(256) void vq_argmin_mfma(const float* __restrict__ inp,
                                                      const int4* __restrict__ packedW,
                                                      const float* __restrict__ wsqb,
                                                      unsigned long long* __restrict__ bestk,
                                                      unsigned* __restrict__ secd) {
    __shared__ int4 sB[2048];   // 32 KB: two 16 KB buffers (4 code-tiles each)
    int wave = threadIdx.x >> 6;
    int lane = threadIdx.x & 63;
    int rbase = blockIdx.x * 128 + wave * 32;
    int kbase = blockIdx.y * KCHUNK;

    int kq = (lane >> 4) * 8;
    bf16x8 ah[2][2], al[2][2];   // [row-tile][k-chunk]
#pragma unroll
    for (int rt = 0; rt < 2; rt++) {
        const float* xp = inp + (size_t)(rbase + rt * 16 + (lane & 15)) * DIM;
#pragma unroll
        for (int kc = 0; kc < 2; kc++) {
            const float* xq = xp + kc * 32 + kq;
#pragma unroll
            for (int j = 0; j < 8; j++) {
                float a = xq[j];
                unsigned short h = bf16_rne(a);
                ah[rt][kc][j] = (short)h;
                al[rt][kc][j] = (short)bf16_rne(a - bf16_to_f(h));
            }
        }
    }

    unsigned best[8], sec[8];
#pragma unroll
    for (int s = 0; s < 8; s++) { best[s] = 0xFFFFFFFFu; sec[s] = 0xFFFFFFFFu; }

    // stage one 16 KB group (4 tiles, wave w stages tile w) into buffer `buf`
#define STAGE(buf, g) do {                                                        \
        const char* _src = (const char*)packedW +                                 \
            ((size_t)(kbase >> 4) + (size_t)(g) * 4 + wave) * 4096;               \
        char* _dst = (char*)sB + (buf) * 16384 + wave * 4096;                     \
        _Pragma("unroll")                                                         \
        for (int _i = 0; _i < 4; _i++)                                            \
            __builtin_amdgcn_global_load_lds(                                     \
                (const __attribute__((address_space(1))) unsigned int*)(_src + _i * 1024 + lane * 16), \
                (__attribute__((address_space(3))) unsigned int*)(_dst + _i * 1024), \
                16, 0, 0);                                                        \
    } while (0)

    STAGE(0, 0);
    __syncthreads();   // drains vmcnt(0): buf0 ready

    for (int g = 0; g < 32; g++) {
        int buf = g & 1;
        if (g + 1 < 32) STAGE(buf ^ 1, g + 1);   // issue next-group loads FIRST
        int lane_code = kbase + g * 64 + (lane & 15);
#pragma unroll
        for (int t = 0; t < 4; t++) {
            const int4* bp = sB + buf * 1024 + t * 256;
            union { int4 q; bf16x8 v; } bh0, bh1, bl0, bl1;
            bh0.q = bp[0 * 64 + lane];
            bh1.q = bp[1 * 64 + lane];
            bl0.q = bp[2 * 64 + lane];
            bl1.q = bp[3 * 64 + lane];
            float wq = wsqb[lane_code + t * 16];
            unsigned tid7 = (unsigned)(g * 4 + t);   // 0..127 tile id in chunk
#pragma unroll
            for (int rt = 0; rt < 2; rt++) {
                f32x4 acc = {wq, wq, wq, wq};   // c = wsq + 8 - 2*dot, directly
                acc = __builtin_amdgcn_mfma_f32_16x16x32_bf16(ah[rt][0], bh0.v, acc, 0, 0, 0);
                acc = __builtin_amdgcn_mfma_f32_16x16x32_bf16(ah[rt][1], bh1.v, acc, 0, 0, 0);
                acc = __builtin_amdgcn_mfma_f32_16x16x32_bf16(al[rt][0], bh0.v, acc, 0, 0, 0);
                acc = __builtin_amdgcn_mfma_f32_16x16x32_bf16(al[rt][1], bh1.v, acc, 0, 0, 0);
                acc = __builtin_amdgcn_mfma_f32_16x16x32_bf16(ah[rt][0], bl0.v, acc, 0, 0, 0);
                acc = __builtin_amdgcn_mfma_f32_16x16x32_bf16(ah[rt][1], bl1.v, acc, 0, 0, 0);
#pragma unroll
                for (int r = 0; r < 4; r++) {
                    unsigned key = (__float_as_uint(acc[r]) & KEYMASK) | tid7;
                    int s = rt * 4 + r;
                    unsigned mx = best[s] > key ? best[s] : key;
                    sec[s] = sec[s] < mx ? sec[s] : mx;
                    best[s] = best[s] < key ? best[s] : key;
                }
            }
        }
        __syncthreads();   // one barrier per group; also drains next-group loads
    }
#undef STAGE

    unsigned col[8];
#pragma unroll
    for (int s = 0; s < 8; s++) col[s] = lane & 15;
#pragma unroll
    for (int m = 1; m < 16; m <<= 1) {
#pragma unroll
        for (int s = 0; s < 8; s++) {
            unsigned ok = (unsigned)__shfl_xor((int)best[s], m, 64);
            unsigned os = (unsigned)__shfl_xor((int)sec[s], m, 64);
            unsigned oc = (unsigned)__shfl_xor((int)col[s], m, 64);
            unsigned mx = best[s] > ok ? best[s] : ok;
            unsigned mn2 = sec[s] < os ? sec[s] : os;
            sec[s] = mn2 < mx ? mn2 : mx;
            bool take = ok < best[s];
            best[s] = take ? ok : best[s];
            col[s] = take ? oc : col[s];
        }
    }
    if ((lane & 15) == 0) {
        int g4 = lane >> 4;
#pragma unroll
        for (int rt = 0; rt < 2; rt++)
#pragma unroll
            for (int r = 0; r < 4; r++) {
                int row = rbase + rt * 16 + g4 * 4 + r;
                int s = rt * 4 + r;
                int code = kbase + (int)(best[s] & 127u) * 16 + (int)col[s];
                bestk[(size_t)blockIdx.y * N_ROWS + row] =
                    ((unsigned long long)best[s] << 32) | (unsigned)code;
                secd[(size_t)blockIdx.y * N_ROWS + row] = sec[s];
            }
    }
}

// ---------------- kernel 2: fused merge + COALESCED recheck + final ----------
// grid 512 x 256. Block owns rows [bx*64, bx*64+64): merge (idx in LDS) ->
// flagged rows rescanned in batches of RB=4 with ONE coalesced codebook sweep
// per batch via wT -> gather/STE/loss. No cross-block data flow.
__global__ __launch_bounds__(256) void vq_tail(const float* __restrict__ inp,
                                               const float* __restrict__ weight,
                                               const float* __restrict__ wsq,
                                               const float* __restrict__ wT,
                                               const unsigned long long* __restrict__ bestk,
                                               const unsigned* __restrict__ secd,
                                               float* __restrict__ out) {
    __shared__ int idx_lds[TROWS];
    __shared__ int rowlist[TROWS];
    __shared__ int nf_s;
    __shared__ float xs[RB][DIM];
    __shared__ float x2s[RB];
    __shared__ unsigned long long wk[4];
    __shared__ float red[4];

    int tid = threadIdx.x;
    int lane = tid & 63;
    int wave = tid >> 6;
    int rbase = blockIdx.x * TROWS;

    if (tid == 0) nf_s = 0;
    __syncthreads();

    // ---- Phase A: merge KSPLIT chunks (proven merge math) ----
    if (tid < TROWS) {
        int row = rbase + tid;
        unsigned long long ks[KSPLIT];
        unsigned ss[KSPLIT];
#pragma unroll
        for (int c = 0; c < KSPLIT; c++) {
            ks[c] = bestk[(size_t)c * N_ROWS + row];
            ss[c] = secd[(size_t)c * N_ROWS + row];
        }
        unsigned long long k1 = ks[0];
#pragma unroll
        for (int c = 1; c < KSPLIT; c++) k1 = (ks[c] < k1) ? ks[c] : k1;
        unsigned d2 = 0xFFFFFFFFu;
#pragma unroll
        for (int c = 0; c < KSPLIT; c++) {
            if (ks[c] != k1) {
                unsigned b = (unsigned)(ks[c] >> 32);
                d2 = b < d2 ? b : d2;
            }
            d2 = ss[c] < d2 ? ss[c] : d2;
        }
        idx_lds[tid] = (int)(k1 & 0xffffffffull);
        float f1 = __uint_as_float(((unsigned)(k1 >> 32)) & KEYMASK);
        float f2 = __uint_as_float(d2 & KEYMASK);
        if (f2 - f1 < MARGIN) {
            int slot = atomicAdd(&nf_s, 1);
            rowlist[slot] = tid;       // local row id
        }
    }
    __syncthreads();
    int nf = nf_s;

    // ---- Phase B: batched rescan via transposed codebook (coalesced) ----
    for (int f0 = 0; f0 < nf; f0 += RB) {
        int nr = nf - f0; if (nr > RB) nr = RB;

        for (int e = tid; e < nr * DIM; e += 256) {
            int r = e >> 6;
            xs[r][e & 63] = inp[(size_t)(rbase + rowlist[f0 + r]) * DIM + (e & 63)];
        }
        __syncthreads();
        if (tid < nr) x2s[tid] = np_pairwise_sq64(xs[tid]);
        __syncthreads();

        unsigned long long bkey[RB];
#pragma unroll
        for (int r = 0; r < RB; r++) bkey[r] = 0xFFFFFFFFFFFFFFFFull;

#pragma unroll 1   // serial over code-quads (register budget: R13/R16 lesson)
        for (int it = 0; it < K_CODES / 1024; ++it) {   // 8 iters, 4 codes/thread
            int code0 = it * 1024 + tid * 4;
            float s[RB][4];
#pragma unroll
            for (int r = 0; r < RB; r++)
#pragma unroll
                for (int q = 0; q < 4; q++) s[r][q] = 0.f;
#pragma unroll 4   // 4 float4 of wT in flight (16 VGPR)
            for (int i = 0; i < DIM; ++i) {
                float4 w4 = *(const float4*)(wT + (size_t)i * K_CODES + code0);
#pragma unroll
                for (int r = 0; r < RB; r++) {
                    float xv = xs[r][i];
                    s[r][0] = __builtin_fmaf(xv, w4.x, s[r][0]);
                    s[r][1] = __builtin_fmaf(xv, w4.y, s[r][1]);
                    s[r][2] = __builtin_fmaf(xv, w4.z, s[r][2]);
                    s[r][3] = __builtin_fmaf(xv, w4.w, s[r][3]);
                }
            }
            float4 wsq4 = *(const float4*)(wsq + code0);
#pragma unroll
            for (int r = 0; r < RB; r++) {
                float w0 = wsq4.x, w1 = wsq4.y, w2 = wsq4.z, w3 = wsq4.w;
                float d0 = __fsub_rn(__fadd_rn(x2s[r], w0), __fmul_rn(2.0f, s[r][0]));
                float d1 = __fsub_rn(__fadd_rn(x2s[r], w1), __fmul_rn(2.0f, s[r][1]));
                float d2 = __fsub_rn(__fadd_rn(x2s[r], w2), __fmul_rn(2.0f, s[r][2]));
                float d3 = __fsub_rn(__fadd_rn(x2s[r], w3), __fmul_rn(2.0f, s[r][3]));
                unsigned long long k0 = ((unsigned long long)f2u_ord(d0) << 32) | (unsigned)(code0 + 0);
                unsigned long long k1 = ((unsigned long long)f2u_ord(d1) << 32) | (unsigned)(code0 + 1);
                unsigned long long k2 = ((unsigned long long)f2u_ord(d2) << 32) | (unsigned)(code0 + 2);
                unsigned long long k3 = ((unsigned long long)f2u_ord(d3) << 32) | (unsigned)(code0 + 3);
                unsigned long long m01 = k0 < k1 ? k0 : k1;
                unsigned long long m23 = k2 < k3 ? k2 : k3;
                unsigned long long m = m01 < m23 ? m01 : m23;
                bkey[r] = m < bkey[r] ? m : bkey[r];
            }
        }

        // per-row reduce: wave shuffle-min -> LDS -> thread 0 writes idx_lds
#pragma unroll 1
        for (int r = 0; r < RB; r++) {
            if (r >= nr) break;   // nr is block-uniform: no divergence hazard
            unsigned long long k = bkey[r];
#pragma unroll
            for (int m = 1; m < 64; m <<= 1) {
                unsigned hi = (unsigned)(k >> 32), lo = (unsigned)k;
                unsigned ohi = (unsigned)__shfl_xor((int)hi, m, 64);
                unsigned olo = (unsigned)__shfl_xor((int)lo, m, 64);
                unsigned long long o = ((unsigned long long)ohi << 32) | olo;
                k = o < k ? o : k;
            }
            if (lane == 0) wk[wave] = k;
            __syncthreads();
            if (tid == 0) {
                unsigned long long kk = wk[0];
#pragma unroll
                for (int w = 1; w < 4; w++) kk = wk[w] < kk ? wk[w] : kk;
                idx_lds[rowlist[f0 + r]] = (int)(kk & 0xffffffffull);
            }
            __syncthreads();
        }
    }

    // ---- Phase C: gather + STE + loss + index (from LDS idx) ----
    float lp = 0.f;
#pragma unroll
    for (int i = 0; i < (TROWS * 16) / 256; ++i) {   // 4 float4 per thread
        int e = i * 256 + tid;
        int lr = e >> 4;
        int sub = e & 15;
        int row = rbase + lr;
        int idx = idx_lds[lr];

        float4 x = ((const float4*)inp)[(size_t)row * 16 + sub];
        float4 w = ((const float4*)weight)[(size_t)idx * 16 + sub];

        float4 q;
        q.x = x.x + (w.x - x.x);
        q.y = x.y + (w.y - x.y);
        q.z = x.z + (w.z - x.z);
        q.w = x.w + (w.w - x.w);
        ((float4*)(out + OUT_Q))[(size_t)row * 16 + sub] = q;

        if (sub == 0) out[OUT_IDX + row] = (float)idx;

        float dx = w.x - x.x, dy = w.y - x.y, dz = w.z - x.z, dw = w.w - x.w;
        lp += dx * dx + dy * dy + dz * dz + dw * dw;
    }
#pragma unroll
    for (int o = 32; o > 0; o >>= 1) lp += __shfl_down(lp, o, 64);
    if (lane == 0) red[wave] = lp;
    __syncthreads();
    if (tid == 0) {
        float bs = red[0] + red[1] + red[2] + red[3];
        atomicAdd(out + OUT_LOSS, bs * (0.25f / 2097152.f));
    }
}

extern "C" void kernel_launch(void* const* d_in, const int* in_sizes, int n_in,
                              void* d_out, int out_size, void* d_ws, size_t ws_size,
                              hipStream_t stream) {
    const float* inp = (const float*)d_in[0];
    const float* weight = (const float*)d_in[1];
    float* out = (float*)d_out;

    char* p = (char*)d_ws;
    unsigned long long* bestk = (unsigned long long*)p; p += (size_t)KSPLIT * N_ROWS * 8; // 1 MB
    unsigned* secd  = (unsigned*)p;            p += (size_t)KSPLIT * N_ROWS * 4;          // 512 KB
    float* wsq      = (float*)p;               p += (size_t)K_CODES * 4;                  // 32 KB
    float* wsqb     = (float*)p;               p += (size_t)K_CODES * 4;                  // 32 KB
    int4* packedW   = (int4*)p;                p += (size_t)512 * 4 * 64 * 16;            // 2 MB
    float* wT       = (float*)p;               p += (size_t)DIM * K_CODES * 4;            // 2 MB

    vq_prep<<<128, 256, 0, stream>>>(weight, wsq, wsqb, packedW, wT, out + OUT_LOSS);
    vq_argmin_mfma<<<dim3(N_ROWS / 128, KSPLIT), 256, 0, stream>>>(
        inp, packedW, wsqb, bestk, secd);
    vq_tail<<<N_ROWS / TROWS, 256, 0, stream>>>(inp, weight, wsq, wT, bestk, secd, out);
}